// Round 1
// baseline (428.511 us; speedup 1.0000x reference)
//
#include <hip/hip_runtime.h>
#include <hip/hip_bf16.h>
#include <math.h>

// Problem constants
#define NN   16
#define CI   64
#define HH   224
#define WW   224
#define CO   128
#define OHH  222
#define OWW  222

// ws holds ONLY prep_w's B fragments (144 KB) -> tiny poison cost.
#define WS_NEED (36*4*64*16)   // 147456

typedef short  short8  __attribute__((ext_vector_type(8)));
typedef float  f32x16  __attribute__((ext_vector_type(16)));
typedef float  f32x4   __attribute__((ext_vector_type(4)));

__device__ static inline unsigned f2bf_pk(float a, float b) {
  __hip_bfloat162 h = __float22bfloat162_rn(make_float2(a, b));  // v_cvt_pk_bf16_f32
  return *reinterpret_cast<unsigned*>(&h);
}

// ---------------------------------------------------------------------------
// prep_w: weights [Co][Ci][3][3] fp32 -> B fragments in mfma lane order.
// frag (s, ctg): s = tap*4+cic (tap=kh*3+kw), ctg 0..3; element ((s*4+ctg)*64+lane).
// B[k][n]: n = lane&31 (co within 32-tile), k = (lane>>5)*8 + j.  (UNCHANGED)
// ---------------------------------------------------------------------------
__global__ __launch_bounds__(256) void prep_w_kernel(const float* __restrict__ wt,
                                                     unsigned char* __restrict__ ws) {
  int t    = blockIdx.x * 256 + threadIdx.x;       // 0..9215
  int lane = t & 63;
  int f    = t >> 6;                               // 0..143
  int s    = f >> 2;
  int ct   = f & 3;
  int tap  = s >> 2;
  int cic  = s & 3;
  int kh   = tap / 3, kw = tap % 3;
  int co   = ct * 32 + (lane & 31);
  int k0   = cic * 16 + (lane >> 5) * 8;
  unsigned pk[4];
#pragma unroll
  for (int j = 0; j < 4; ++j) {
    int ci0 = k0 + 2 * j;
    float a = wt[(size_t)co * 576 + (ci0    ) * 9 + kh * 3 + kw];
    float b = wt[(size_t)co * 576 + (ci0 + 1) * 9 + kh * 3 + kw];
    pk[j] = f2bf_pk(a, b);
  }
  ((uint4*)ws)[t] = make_uint4(pk[0], pk[1], pk[2], pk[3]);
}

// ---------------------------------------------------------------------------
// conv v4: occupancy-doubled tile.
// Block 256 thr / 4 waves covers 4 oh x 32 ow x 128 co.
// Wave (mg = wv>>1, ng = wv&1): 2 m-tiles (oh rows mg*2+ohl) x 2 co-tiles;
// acc[2][2] = 64 regs (was 128); LDS 6 x 34 x 128 = 26112 B (was 55296).
// -> 4 blocks/CU (16 waves, 50% occ) vs previous 2 blocks (8 waves, 23%).
// A staged in-kernel from NCHW fp32 (bank-rotated bf16 slots); B from ws via
// register triple-buffer; ds_read addresses are P[j] + compile-time offset.
// ---------------------------------------------------------------------------
__global__ __launch_bounds__(256, 4) void conv_min_kernel(
    const float* __restrict__ x, const float* __restrict__ bias,
    const unsigned char* __restrict__ ws, float* __restrict__ out) {
  __shared__ __align__(16) unsigned char smem[6 * 34 * 128];  // 26112 B

  int bid = blockIdx.x;
  // XCD-aware bijective swizzle: grid = 6272 = 8 * 784. Vertical neighbors
  // (bid +/- 7, sharing 2 input rows) land in the same XCD chunk.
  bid = (bid & 7) * (NN * 56 * 7 / 8) + (bid >> 3);

  int owt  = bid % 7;
  int rest = bid / 7;
  int oht  = rest % 56;
  int n    = rest / 56;
  int ow0  = (owt < 6) ? owt * 32 : 190;   // last ow tile overlaps (same values)
  int oh0  = oht * 4;                      // oh 222/223 masked at store

  int tid   = threadIdx.x;
  int wv    = tid >> 6;
  int lane  = tid & 63;
  int mg    = wv >> 1;     // oh row-pair
  int ng    = wv & 1;      // co half
  int mrow  = lane & 31;
  int khalf = lane >> 5;

  // ---- B prologue (issue before staging so loads overlap) ----
  const short8* wf = (const short8*)ws;
  int bbase = ng * 128 + lane;
  short8 bb[3][2];
#pragma unroll
  for (int ct = 0; ct < 2; ++ct) bb[0][ct] = wf[0 * 256 + ct * 64 + bbase];
#pragma unroll
  for (int ct = 0; ct < 2; ++ct) bb[1][ct] = wf[1 * 256 + ct * 64 + bbase];

  // ---- in-kernel A staging: 6 rows x 34 cols x 64 ci bf16, rotated slots ----
  // slot(row,col): chunk cc (ci 8cc..8cc+7) at byte ((cc+col)&7)*16, word pp&3.
  {
    int colm = (tid & 15) * 2;     // main cols 0..31 (pairs)
    int q    = tid >> 4;           // ci-pair group 0..15
    const float* xb = x + (size_t)n * 64 * 50176;
#pragma unroll 1
    for (int r = 0; r < 6; ++r) {
      int rg = oh0 + r; if (rg > 223) rg = 223;
      const float* xr = xb + (size_t)rg * 224;
#pragma unroll
      for (int p = 0; p < 2; ++p) {
        int pp = p * 16 + q;       // 0..31
        int ci = pp * 2;
        const float* s0 = xr + (size_t)ci * 50176 + ow0 + colm;
        float2 a2 = *(const float2*)s0;
        float2 b2 = *(const float2*)(s0 + 50176);
        unsigned u0 = f2bf_pk(a2.x, b2.x);
        unsigned u1 = f2bf_pk(a2.y, b2.y);
        int cc = pp >> 2, jw = (pp & 3) * 4;
        *(unsigned*)(smem + (r * 34 + colm    ) * 128 + (((cc + colm    ) & 7) << 4) + jw) = u0;
        *(unsigned*)(smem + (r * 34 + colm + 1) * 128 + (((cc + colm + 1) & 7) << 4) + jw) = u1;
      }
      if (tid < 64) {   // halo cols 32,33 (ow0+33 <= 223: never OOB)
        int cole = 32 + (tid & 1);
        int ppe  = tid >> 1;       // 0..31
        const float* s0 = xr + (size_t)(ppe * 2) * 50176 + ow0 + cole;
        float a = s0[0], b = s0[50176];
        *(unsigned*)(smem + (r * 34 + cole) * 128 + ((((ppe >> 2) + cole) & 7) << 4) + (ppe & 3) * 4) =
            f2bf_pk(a, b);
      }
    }
  }

  // ---- acc init with bias ----
  f32x16 acc[2][2];
#pragma unroll
  for (int ct = 0; ct < 2; ++ct) {
    float bv = bias[ng * 64 + ct * 32 + mrow];
#pragma unroll
    for (int ohl = 0; ohl < 2; ++ohl)
#pragma unroll
      for (int r = 0; r < 16; ++r) acc[ohl][ct][r] = bv;
  }

  // ---- zero-VALU LDS read pointers ----
  unsigned uu = (mrow + khalf) & 7;
  const unsigned char* Pb = smem + mg * (2 * 34 * 128) + mrow * 128;
  const unsigned char* P[8];
#pragma unroll
  for (int j = 0; j < 8; ++j) P[j] = Pb + ((uu + j) & 7) * 16;

  __syncthreads();

  // ---- A preload step 0 ----
  short8 aa[2][2];
#pragma unroll
  for (int ohl = 0; ohl < 2; ++ohl)
    aa[0][ohl] = *(const short8*)(P[0] + ((ohl * 34) << 7));

  // ---- K loop: 36 steps (tap,cic), fully unrolled, barrier-free ----
#pragma unroll
  for (int s = 0; s < 36; ++s) {
    if (s + 2 < 36) {
#pragma unroll
      for (int ct = 0; ct < 2; ++ct)
        bb[(s + 2) % 3][ct] = wf[(s + 2) * 256 + ct * 64 + bbase];
    }
    if (s + 1 < 36) {
      const int s1 = s + 1;
      const int kh1 = s1 / 12, kw1 = (s1 / 4) % 3, cic1 = s1 & 3;
      const int j1 = (2 * cic1 + kw1) & 7;
#pragma unroll
      for (int ohl = 0; ohl < 2; ++ohl)
        aa[s1 & 1][ohl] =
            *(const short8*)(P[j1] + ((((ohl + kh1) * 34) + kw1) << 7));
    }
#pragma unroll
    for (int ohl = 0; ohl < 2; ++ohl)
#pragma unroll
      for (int ct = 0; ct < 2; ++ct)
        acc[ohl][ct] = __builtin_amdgcn_mfma_f32_32x32x16_bf16(
            aa[s & 1][ohl], bb[s % 3][ct], acc[ohl][ct], 0, 0, 0);
  }

  // ---- epilogue ----
  // C/D: col = lane&31 (co), row = (r&3)+8*(r>>2)+4*khalf (pixel m = ow).
  __syncthreads();          // A-tile dead; reuse smem for reduction
  float* epi = (float*)smem;  // [px 128][36 words]: ng*16 + co' in words 0..31
#pragma unroll
  for (int ohl = 0; ohl < 2; ++ohl) {
#pragma unroll
    for (int r = 0; r < 16; ++r) {
      float v = fminf(acc[ohl][0][r], acc[ohl][1][r]);       // min over ct
      v = fminf(v, __shfl_xor(v, 16, 64));                   // min over co pairs
      if ((lane & 16) == 0) {
        int px = (mg * 2 + ohl) * 32 + ((r & 3) + 8 * (r >> 2) + 4 * khalf);
        epi[px * 36 + ng * 16 + (lane & 15)] = v;
      }
    }
  }
  __syncthreads();
  if (tid < 128) {
    int px = tid;
    int oh = oh0 + (px >> 5);
    const f32x4* rowp = (const f32x4*)(epi + px * 36);
    f32x4 m4 = rowp[0];
#pragma unroll
    for (int k = 1; k < 8; ++k) {
      f32x4 t = rowp[k];
      m4[0] = fminf(m4[0], t[0]); m4[1] = fminf(m4[1], t[1]);
      m4[2] = fminf(m4[2], t[2]); m4[3] = fminf(m4[3], t[3]);
    }
    float v = fminf(fminf(m4[0], m4[1]), fminf(m4[2], m4[3]));
    v = tanhf(tanhf(v));
    if (oh < OHH)
      out[(size_t)n * (OHH * OWW) + (size_t)oh * OWW + ow0 + (px & 31)] = v;
  }
}

// ---------------------------------------------------------------------------
// Fallback (only if ws too small): direct fp32 conv, 8 px per block.
// ---------------------------------------------------------------------------
__global__ __launch_bounds__(128) void fallback_kernel(
    const float* __restrict__ x, const float* __restrict__ wt,
    const float* __restrict__ bias, float* __restrict__ out) {
  __shared__ float patch[64 * 30];
  __shared__ float red[128];
  int pb   = blockIdx.x;
  int owt  = pb % 28;
  int rest = pb / 28;
  int oh   = rest % OHH;
  int n    = rest / OHH;
  int ow0  = owt * 8;
  int tid  = threadIdx.x;
  for (int i = tid; i < 1920; i += 128) {
    int wl = i % 10;
    int rr = (i / 10) % 3;
    int ci = i / 30;
    int wg = ow0 + wl;
    float v = 0.f;
    if (wg < WW) v = x[((size_t)(n * 64 + ci) * HH + (oh + rr)) * WW + wg];
    patch[i] = v;
  }
  __syncthreads();
  int co = tid;
  float a[8];
#pragma unroll
  for (int p = 0; p < 8; ++p) a[p] = bias[co];
  for (int ci = 0; ci < 64; ++ci) {
#pragma unroll
    for (int rr = 0; rr < 3; ++rr)
#pragma unroll
      for (int kw = 0; kw < 3; ++kw) {
        float wvv = wt[(size_t)co * 576 + ci * 9 + rr * 3 + kw];
        const float* pp = &patch[ci * 30 + rr * 10 + kw];
#pragma unroll
        for (int p = 0; p < 8; ++p) a[p] += pp[p] * wvv;
      }
  }
  for (int p = 0; p < 8; ++p) {
    red[tid] = a[p];
    __syncthreads();
    for (int st = 64; st > 0; st >>= 1) {
      if (tid < st) red[tid] = fminf(red[tid], red[tid + st]);
      __syncthreads();
    }
    if (tid == 0 && (ow0 + p) < OWW)
      out[(size_t)n * (OHH * OWW) + (size_t)oh * OWW + ow0 + p] = tanhf(tanhf(red[0]));
    __syncthreads();
  }
}

// ---------------------------------------------------------------------------
extern "C" void kernel_launch(void* const* d_in, const int* in_sizes, int n_in,
                              void* d_out, int out_size, void* d_ws, size_t ws_size,
                              hipStream_t stream) {
  const float* x    = (const float*)d_in[0];
  const float* wt   = (const float*)d_in[1];
  const float* bias = (const float*)d_in[2];
  float* out        = (float*)d_out;

  if (ws_size >= WS_NEED) {
    unsigned char* ws = (unsigned char*)d_ws;
    prep_w_kernel<<<36, 256, 0, stream>>>(wt, ws);
    conv_min_kernel<<<NN * 56 * 7, 256, 0, stream>>>(x, bias, ws, out);
  } else {
    fallback_kernel<<<NN * OHH * 28, 128, 0, stream>>>(x, wt, bias, out);
  }
}

// Round 2
// 427.797 us; speedup vs baseline: 1.0017x; 1.0017x over previous
//
#include <hip/hip_runtime.h>
#include <hip/hip_bf16.h>
#include <math.h>

// Problem constants
#define NN   16
#define CI   64
#define HH   224
#define WW   224
#define CO   128
#define OHH  222
#define OWW  222

// ws holds ONLY prep_w's B fragments (144 KB) -> tiny poison cost.
#define WS_NEED (36*4*64*16)   // 147456

typedef short  short8  __attribute__((ext_vector_type(8)));
typedef float  f32x16  __attribute__((ext_vector_type(16)));
typedef float  f32x4   __attribute__((ext_vector_type(4)));

__device__ static inline unsigned f2bf_pk(float a, float b) {
  __hip_bfloat162 h = __float22bfloat162_rn(make_float2(a, b));  // v_cvt_pk_bf16_f32
  return *reinterpret_cast<unsigned*>(&h);
}

// ---------------------------------------------------------------------------
// prep_w: weights [Co][Ci][3][3] fp32 -> B fragments in mfma lane order.
// frag (s, ctg): s = tap*4+cic (tap=kh*3+kw), ctg 0..3; element ((s*4+ctg)*64+lane).
// B[k][n]: n = lane&31 (co within 32-tile), k = (lane>>5)*8 + j.  (UNCHANGED)
// ---------------------------------------------------------------------------
__global__ __launch_bounds__(256) void prep_w_kernel(const float* __restrict__ wt,
                                                     unsigned char* __restrict__ ws) {
  int t    = blockIdx.x * 256 + threadIdx.x;       // 0..9215
  int lane = t & 63;
  int f    = t >> 6;                               // 0..143
  int s    = f >> 2;
  int ct   = f & 3;
  int tap  = s >> 2;
  int cic  = s & 3;
  int kh   = tap / 3, kw = tap % 3;
  int co   = ct * 32 + (lane & 31);
  int k0   = cic * 16 + (lane >> 5) * 8;
  unsigned pk[4];
#pragma unroll
  for (int j = 0; j < 4; ++j) {
    int ci0 = k0 + 2 * j;
    float a = wt[(size_t)co * 576 + (ci0    ) * 9 + kh * 3 + kw];
    float b = wt[(size_t)co * 576 + (ci0 + 1) * 9 + kh * 3 + kw];
    pk[j] = f2bf_pk(a, b);
  }
  ((uint4*)ws)[t] = make_uint4(pk[0], pk[1], pk[2], pk[3]);
}

// ---------------------------------------------------------------------------
// conv v5: spill-free occupancy doubling.
// Block 512 thr / 8 waves covers 4 oh x 32 ow x 128 co (same tile/staging as v4,
// so no extra halo fetch). Wave (mg = wv>>1 = oh row, ng = wv&1 = co half):
// 1 m-tile x 2 ct -> acc[2] f32x16 = 32 VGPR (v4's 64 at 256thr spilled: the
// (256,4) 128-reg budget couldn't hold 64 acc + frags -> 150 MB scratch writes).
// Steady state here: acc 32 + aa 8 + bb 24 + P 8 + addr ~= 100 < 128.
// __launch_bounds__(512,4): 2 blocks/CU = 16 waves (50% occ), LDS 26112 B.
// ---------------------------------------------------------------------------
__global__ __launch_bounds__(512, 4) void conv_min_kernel(
    const float* __restrict__ x, const float* __restrict__ bias,
    const unsigned char* __restrict__ ws, float* __restrict__ out) {
  __shared__ __align__(16) unsigned char smem[6 * 34 * 128];  // 26112 B

  int bid = blockIdx.x;
  // XCD-aware bijective swizzle: grid = 6272 = 8 * 784. Vertical neighbors
  // (bid +/- 7, sharing 2 input rows) land in the same XCD chunk.
  bid = (bid & 7) * (NN * 56 * 7 / 8) + (bid >> 3);

  int owt  = bid % 7;
  int rest = bid / 7;
  int oht  = rest % 56;
  int n    = rest / 56;
  int ow0  = (owt < 6) ? owt * 32 : 190;   // last ow tile overlaps (same values)
  int oh0  = oht * 4;                      // oh 222/223 masked at store

  int tid   = threadIdx.x;
  int wv    = tid >> 6;    // 0..7
  int lane  = tid & 63;
  int mg    = wv >> 1;     // oh row 0..3
  int ng    = wv & 1;      // co half
  int mrow  = lane & 31;
  int khalf = lane >> 5;

  // ---- B prologue (issue before staging so loads overlap) ----
  const short8* wf = (const short8*)ws;
  int bbase = ng * 128 + lane;
  short8 bb[3][2];
#pragma unroll
  for (int ct = 0; ct < 2; ++ct) bb[0][ct] = wf[0 * 256 + ct * 64 + bbase];
#pragma unroll
  for (int ct = 0; ct < 2; ++ct) bb[1][ct] = wf[1 * 256 + ct * 64 + bbase];

  // ---- in-kernel A staging: 6 rows x 34 cols x 64 ci bf16, rotated slots ----
  // slot(row,col): chunk cc (ci 8cc..8cc+7) at byte ((cc+col)&7)*16, word pp&3.
  // 512 threads: each thread does ONE (col-pair, ci-pair) per row.
  {
    int colm = (tid & 15) * 2;     // main cols 0..31 (pairs)
    int q    = tid >> 4;           // ci-pair 0..31
    const float* xb = x + (size_t)n * 64 * 50176;
#pragma unroll 1
    for (int r = 0; r < 6; ++r) {
      int rg = oh0 + r; if (rg > 223) rg = 223;
      const float* xr = xb + (size_t)rg * 224;
      {
        int ci = q * 2;
        const float* s0 = xr + (size_t)ci * 50176 + ow0 + colm;
        float2 a2 = *(const float2*)s0;
        float2 b2 = *(const float2*)(s0 + 50176);
        unsigned u0 = f2bf_pk(a2.x, b2.x);
        unsigned u1 = f2bf_pk(a2.y, b2.y);
        int cc = q >> 2, jw = (q & 3) * 4;
        *(unsigned*)(smem + (r * 34 + colm    ) * 128 + (((cc + colm    ) & 7) << 4) + jw) = u0;
        *(unsigned*)(smem + (r * 34 + colm + 1) * 128 + (((cc + colm + 1) & 7) << 4) + jw) = u1;
      }
      if (tid < 64) {   // halo cols 32,33 (ow0+33 <= 223: never OOB)
        int cole = 32 + (tid & 1);
        int ppe  = tid >> 1;       // 0..31
        const float* s0 = xr + (size_t)(ppe * 2) * 50176 + ow0 + cole;
        float a = s0[0], b = s0[50176];
        *(unsigned*)(smem + (r * 34 + cole) * 128 + ((((ppe >> 2) + cole) & 7) << 4) + (ppe & 3) * 4) =
            f2bf_pk(a, b);
      }
    }
  }

  // ---- acc init with bias ----
  f32x16 acc[2];
#pragma unroll
  for (int ct = 0; ct < 2; ++ct) {
    float bv = bias[ng * 64 + ct * 32 + mrow];
#pragma unroll
    for (int r = 0; r < 16; ++r) acc[ct][r] = bv;
  }

  // ---- zero-VALU LDS read pointers ----
  unsigned uu = (mrow + khalf) & 7;
  const unsigned char* Pb = smem + (mg * 34 + mrow) * 128;
  const unsigned char* P[8];
#pragma unroll
  for (int j = 0; j < 8; ++j) P[j] = Pb + ((uu + j) & 7) * 16;

  __syncthreads();

  // ---- A preload step 0 (s=0: kh=kw=0, cic=0 -> j=0, offset 0) ----
  short8 aa[2];
  aa[0] = *(const short8*)(P[0]);

  // ---- K loop: 36 steps (tap,cic), fully unrolled, barrier-free ----
#pragma unroll
  for (int s = 0; s < 36; ++s) {
    if (s + 2 < 36) {
#pragma unroll
      for (int ct = 0; ct < 2; ++ct)
        bb[(s + 2) % 3][ct] = wf[(s + 2) * 256 + ct * 64 + bbase];
    }
    if (s + 1 < 36) {
      const int s1 = s + 1;
      const int kh1 = s1 / 12, kw1 = (s1 / 4) % 3, cic1 = s1 & 3;
      const int j1 = (2 * cic1 + kw1) & 7;
      aa[s1 & 1] = *(const short8*)(P[j1] + ((kh1 * 34 + kw1) << 7));
    }
#pragma unroll
    for (int ct = 0; ct < 2; ++ct)
      acc[ct] = __builtin_amdgcn_mfma_f32_32x32x16_bf16(
          aa[s & 1], bb[s % 3][ct], acc[ct], 0, 0, 0);
  }

  // ---- epilogue ----
  // C/D: col = lane&31 (co), row = (r&3)+8*(r>>2)+4*khalf (pixel m = ow).
  __syncthreads();          // A-tile dead; reuse smem for reduction
  float* epi = (float*)smem;  // [px 128][36 words]: ng*16 + co' in words 0..31
#pragma unroll
  for (int r = 0; r < 16; ++r) {
    float v = fminf(acc[0][r], acc[1][r]);                 // min over ct
    v = fminf(v, __shfl_xor(v, 16, 64));                   // min over co pairs
    if ((lane & 16) == 0) {
      int px = mg * 32 + ((r & 3) + 8 * (r >> 2) + 4 * khalf);
      epi[px * 36 + ng * 16 + (lane & 15)] = v;
    }
  }
  __syncthreads();
  if (tid < 128) {
    int px = tid;
    int oh = oh0 + (px >> 5);
    const f32x4* rowp = (const f32x4*)(epi + px * 36);
    f32x4 m4 = rowp[0];
#pragma unroll
    for (int k = 1; k < 8; ++k) {
      f32x4 t = rowp[k];
      m4[0] = fminf(m4[0], t[0]); m4[1] = fminf(m4[1], t[1]);
      m4[2] = fminf(m4[2], t[2]); m4[3] = fminf(m4[3], t[3]);
    }
    float v = fminf(fminf(m4[0], m4[1]), fminf(m4[2], m4[3]));
    v = tanhf(tanhf(v));
    if (oh < OHH)
      out[(size_t)n * (OHH * OWW) + (size_t)oh * OWW + ow0 + (px & 31)] = v;
  }
}

// ---------------------------------------------------------------------------
// Fallback (only if ws too small): direct fp32 conv, 8 px per block.
// ---------------------------------------------------------------------------
__global__ __launch_bounds__(128) void fallback_kernel(
    const float* __restrict__ x, const float* __restrict__ wt,
    const float* __restrict__ bias, float* __restrict__ out) {
  __shared__ float patch[64 * 30];
  __shared__ float red[128];
  int pb   = blockIdx.x;
  int owt  = pb % 28;
  int rest = pb / 28;
  int oh   = rest % OHH;
  int n    = rest / OHH;
  int ow0  = owt * 8;
  int tid  = threadIdx.x;
  for (int i = tid; i < 1920; i += 128) {
    int wl = i % 10;
    int rr = (i / 10) % 3;
    int ci = i / 30;
    int wg = ow0 + wl;
    float v = 0.f;
    if (wg < WW) v = x[((size_t)(n * 64 + ci) * HH + (oh + rr)) * WW + wg];
    patch[i] = v;
  }
  __syncthreads();
  int co = tid;
  float a[8];
#pragma unroll
  for (int p = 0; p < 8; ++p) a[p] = bias[co];
  for (int ci = 0; ci < 64; ++ci) {
#pragma unroll
    for (int rr = 0; rr < 3; ++rr)
#pragma unroll
      for (int kw = 0; kw < 3; ++kw) {
        float wvv = wt[(size_t)co * 576 + ci * 9 + rr * 3 + kw];
        const float* pp = &patch[ci * 30 + rr * 10 + kw];
#pragma unroll
        for (int p = 0; p < 8; ++p) a[p] += pp[p] * wvv;
      }
  }
  for (int p = 0; p < 8; ++p) {
    red[tid] = a[p];
    __syncthreads();
    for (int st = 64; st > 0; st >>= 1) {
      if (tid < st) red[tid] = fminf(red[tid], red[tid + st]);
      __syncthreads();
    }
    if (tid == 0 && (ow0 + p) < OWW)
      out[(size_t)n * (OHH * OWW) + (size_t)oh * OWW + ow0 + p] = tanhf(tanhf(red[0]));
    __syncthreads();
  }
}

// ---------------------------------------------------------------------------
extern "C" void kernel_launch(void* const* d_in, const int* in_sizes, int n_in,
                              void* d_out, int out_size, void* d_ws, size_t ws_size,
                              hipStream_t stream) {
  const float* x    = (const float*)d_in[0];
  const float* wt   = (const float*)d_in[1];
  const float* bias = (const float*)d_in[2];
  float* out        = (float*)d_out;

  if (ws_size >= WS_NEED) {
    unsigned char* ws = (unsigned char*)d_ws;
    prep_w_kernel<<<36, 256, 0, stream>>>(wt, ws);
    conv_min_kernel<<<NN * 56 * 7, 512, 0, stream>>>(x, bias, ws, out);
  } else {
    fallback_kernel<<<NN * OHH * 28, 128, 0, stream>>>(x, wt, bias, out);
  }
}